// Round 8
// baseline (99.270 us; speedup 1.0000x reference)
//
#include <hip/hip_runtime.h>

// Fully-fused 3x Minkowski sum-pool (3x3, stride 2, pad 1) with coordinate masks.
// feat (4,1024,1024,16) f32, mask (4,1024,1024) i32 -> out = concat(c2, c3).
// R8 = R7 (pair-row sweep, 512 blocks, 1 barrier/iter) with feat prefetch
// depth 2: pair i+2 issued at iter i (ffA/ffB ping-pong), masks 4 iters ahead
// (3-buffer rotation). 36 iterations (iter 35 = folded epilogue), 6-unrolled
// so all buffers have static register roles.

constexpr int Hh = 1024, Ww = 1024;
constexpr int TW3 = 16, TH3 = 8;           // c3 tile per block
constexpr int NU = 4 * TW3 + 3;            // 67 c1 cols per block
constexpr int NV = 2 * TW3 + 1;            // 33 c2 cols per block
constexpr int NY = TW3;                    // 16 c3 cols
constexpr int NTH = 320;
constexpr int NS = 4 * TH3 + 3;            // 35 c1 rows (pairs 0..34)
constexpr int NITER = NS + 1;              // 36 = 6 x 6

// LDS-only barrier: wait own LDS ops, sync, leave global prefetch in flight.
#define BARRIER_LDS() asm volatile("s_waitcnt lgkmcnt(0)\ns_barrier" ::: "memory")

__device__ inline float4 add3(const float4& a, const float4& b, const float4& c) {
    return make_float4(a.x + b.x + c.x, a.y + b.y + c.y,
                       a.z + b.z + c.z, a.w + b.w + c.w);
}

__global__ __launch_bounds__(NTH) void fused3(
    const float* __restrict__ featp, const int* __restrict__ maskp,
    float4* __restrict__ c2o, float4* __restrict__ c3o)
{
    const int j = blockIdx.x;              // col strip (c3 cols [16j,16j+16))
    const int k = blockIdx.y;              // row chunk (c3 rows [8k,8k+8))
    const int b = blockIdx.z;
    const int P0 = TW3 * j, Q0 = TH3 * k;
    const int F0 = 8 * P0 - 7;             // feat col of u=0,dw=0
    const int S0 = 4 * Q0 - 3;             // first c1 row of sweep

    const int tid = threadIdx.x;
    const int c4 = tid & 3;                // which float4 of 16 channels
    const int u  = tid >> 2;               // col role index
    const bool aAct = tid < NU * 4;        // 268 threads: rs1/c1 role
    const bool vAct = tid < NV * 4;        // 132 threads: rs2/c2 role
    const bool yAct = tid < NY * 4;        //  64 threads: rs3/c3 role

    __shared__ float4 c1m[2][NU][5];       // double-buffered (write pre-bar, read post-bar)
    __shared__ float4 c2mS[NV][5];         // written post-bar(even i), read post-bar(i+1)
    __shared__ unsigned char m1L[2][NU];
    __shared__ unsigned char m2L[NV];

    const float4* feat4 = reinterpret_cast<const float4*>(featp);
    const float4 z4 = make_float4(0.f, 0.f, 0.f, 0.f);

    auto ldMaskRow = [&](int t, int* mm) {
        mm[0] = mm[1] = mm[2] = 0;
        if (aAct && (unsigned)t < (unsigned)Hh) {
            const int base = (b * Hh + t) * Ww;
#pragma unroll
            for (int dw = 0; dw < 3; ++dw) {
                const int fc = F0 + 2 * u + dw;
                if ((unsigned)fc < (unsigned)Ww) mm[dw] = maskp[base + fc];
            }
        }
    };
    auto ldFeatRow = [&](int t, const int* mm, float4* ff) {
        ff[0] = ff[1] = ff[2] = z4;
        if (aAct && (unsigned)t < (unsigned)Hh) {
            const size_t base = (size_t)(b * Hh + t) * Ww;
#pragma unroll
            for (int dw = 0; dw < 3; ++dw) {
                if (mm[dw])   // masked-out pixels are never fetched
                    ff[dw] = feat4[(base + (F0 + 2 * u + dw)) * 4 + c4];
            }
        }
    };
    // pair p = c1 row S0+p = feat rows 2(S0+p), 2(S0+p)+1
    auto ldMaskPair = [&](int p, int* m6) {
        ldMaskRow(2 * (S0 + p),     m6);
        ldMaskRow(2 * (S0 + p) + 1, m6 + 3);
    };
    auto ldFeatPair = [&](int p, const int* m6, float4* f6) {
        ldFeatRow(2 * (S0 + p),     m6,     f6);
        ldFeatRow(2 * (S0 + p) + 1, m6 + 3, f6 + 3);
    };
    auto occ = [&](const int* m6) { return m6[1] | m6[2] | m6[4] | m6[5]; };

    // ---- prologue: pairs 0,1 feat in flight, masks for pairs 0..3 ----
    int M0[6], M1[6], M2[6];               // mask buffers: pair x -> buf x%3
    float4 ffA[6], ffB[6];                 // feat pair buffers: pair x -> A if x even
    float4 h_prev;
    int mpA, mpB;                          // occupancy of pair i, i+1
    {
        int mP[3];
        ldMaskRow(2 * S0 - 1, mP);
        ldMaskPair(0, M0);
        ldMaskPair(1, M1);
        ldMaskPair(2, M2);
        float4 fP[3];
        ldFeatRow(2 * S0 - 1, mP, fP);     // waits mask wave, issues feat
        ldFeatPair(0, M0, ffA);
        ldFeatPair(1, M1, ffB);
        mpA = occ(M0);
        mpB = occ(M1);
        ldMaskPair(3, M0);                 // pair 3 -> buf 0 (after M0's last use)
        h_prev = add3(fP[0], fP[1], fP[2]);
    }

    float4 r2h0 = z4, r2h1 = z4;           // rs2 history (s-2, s-1)
    float4 r3h0 = z4, r3h1 = z4;           // rs3 history
    int m2save = 0, m3save = 0;

    // body(i): consume FF (pair i); gate-issue pair i+2 into FF with MG
    // (= masks pair i+2); issue masks pair i+4 into MN.
    auto body = [&](int i, float4 (&FF)[6], int (&MG)[6], int (&MN)[6]) {
        const int sb = i & 1;
        // A: consume feat pair i -> c1 row s = S0+i
        const float4 hc_e = add3(FF[0], FF[1], FF[2]);
        const float4 hc_o = add3(FF[3], FF[4], FF[5]);
        if (aAct) {
            float4 cv = z4;
            if (mpA) cv = add3(h_prev, hc_e, hc_o);
            c1m[sb][u][c4] = cv;
            if (c4 == 0) m1L[sb][u] = (unsigned char)(mpA ? 1 : 0);
        }
        h_prev = hc_o;
        mpA = mpB;
        mpB = occ(MG);                     // pair i+2 occupancy
        // B: prefetch — feat pair i+2 (gated by MG), masks pair i+4
        if (i + 2 < NS) ldFeatPair(i + 2, MG, FF);
        if (i + 4 < NS) ldMaskPair(i + 4, MN);
        BARRIER_LDS();                     // the iteration's single barrier
        // C: r2 phase (post-barrier)
        float4 r2c = z4; int m2p = 0;
        if (vAct) {
            r2c = add3(c1m[sb][2 * u + 0][c4], c1m[sb][2 * u + 1][c4],
                       c1m[sb][2 * u + 2][c4]);
            m2p = m1L[sb][2 * u + 1] | m1L[sb][2 * u + 2];
        }
        if ((i & 1) == 0) {
            // c2 row r = 2*Q0 - 2 + i/2 completes; c2mS consumed at i+1
            if (vAct) {
                const int m2 = m2save | m2p;
                float4 c2v = z4;
                if (m2) c2v = add3(r2h0, r2h1, r2c);
                if (i >= 4 && u >= 1) {    // owned rows r>=2Q0, owned cols
                    const int r = 2 * Q0 - 2 + (i >> 1);
                    c2o[((size_t)((b * 256 + r) * 256 + (2 * P0 - 1 + u))) * 4 + c4] = c2v;
                }
                c2mS[u][c4] = c2v;
                if (c4 == 0) m2L[u] = (unsigned char)(m2 ? 1 : 0);
            }
        } else {
            m2save = m2p;
            // D: r3 phase — reads c2 row written post-barrier at i-1
            float4 r3c = z4; int m3p = 0;
            if (yAct) {
                r3c = add3(c2mS[2 * u + 0][c4], c2mS[2 * u + 1][c4],
                           c2mS[2 * u + 2][c4]);
                m3p = m2L[2 * u + 1] | m2L[2 * u + 2];
            }
            if (((i - 1) & 2) == 0) {      // c2 row even: save
                m3save = m3p;
            } else if (yAct && i >= 7) {   // c2 row odd: c3 row q completes
                const int m3 = m3save | m3p;
                float4 c3v = z4;
                if (m3) c3v = add3(r3h0, r3h1, r3c);
                const int q = Q0 + ((i - 7) >> 2);
                c3o[((size_t)((b * 128 + q) * 128 + (P0 + u))) * 4 + c4] = c3v;
            }
            r3h0 = r3h1; r3h1 = r3c;
        }
        r2h0 = r2h1; r2h1 = r2c;
    };

    // 36 iterations, 6-unrolled: ff period 2, mask rotation period 3.
    // slot k: FF = (k odd ? ffB : ffA), MG = M[(k+2)%3], MN = M[(k+1)%3].
    // iter 35 consumes stale/dead data in A/C phases (provably unused) and
    // performs the final r3/c3 store (R7's epilogue folded in).
    for (int ii = 0; ii < NITER; ii += 6) {
        body(ii + 0, ffA, M2, M1);
        body(ii + 1, ffB, M0, M2);
        body(ii + 2, ffA, M1, M0);
        body(ii + 3, ffB, M2, M1);
        body(ii + 4, ffA, M0, M2);
        body(ii + 5, ffB, M1, M0);
    }
}

extern "C" void kernel_launch(void* const* d_in, const int* in_sizes, int n_in,
                              void* d_out, int out_size, void* d_ws, size_t ws_size,
                              hipStream_t stream)
{
    const float* feat = (const float*)d_in[0];
    const int*   mask = (const int*)d_in[1];
    float4* c2 = (float4*)d_out;
    float4* c3 = c2 + (size_t)4 * 256 * 256 * 4;   // 4*256*256*16 floats ahead

    dim3 grid(Ww / (8 * TW3) /*8*/, Hh / (8 * TH3) /*16*/, 4);
    fused3<<<grid, NTH, 0, stream>>>(feat, mask, c2, c3);
}

// Round 9
// 61.524 us; speedup vs baseline: 1.6135x; 1.6135x over previous
//
#include <hip/hip_runtime.h>

// Fully-fused 3x Minkowski sum-pool (3x3, stride 2, pad 1) with coordinate masks.
// feat (4,1024,1024,16) f32, mask (4,1024,1024) i32 -> out = concat(c2, c3).
// R9 = R7 structure (pair-row sweep, 1 barrier/iter, depth-1 prefetch) with
// THIN BLOCKS: TW3=8 -> 192 threads (3 waves), grid 1024 (4 blocks/CU).
// Smaller barrier convoy + more independent blocks per CU; VGPR body unchanged.

constexpr int Hh = 1024, Ww = 1024;
constexpr int TW3 = 8, TH3 = 8;            // c3 tile per block
constexpr int NU = 4 * TW3 + 3;            // 35 c1 cols per block
constexpr int NV = 2 * TW3 + 1;            // 17 c2 cols per block
constexpr int NY = TW3;                    // 8 c3 cols
constexpr int NTH = 192;
constexpr int NS = 4 * TH3 + 3;            // 35 c1 rows per block sweep

// LDS-only barrier: wait own LDS ops, sync, leave global prefetch in flight.
#define BARRIER_LDS() asm volatile("s_waitcnt lgkmcnt(0)\ns_barrier" ::: "memory")

__device__ inline float4 add3(const float4& a, const float4& b, const float4& c) {
    return make_float4(a.x + b.x + c.x, a.y + b.y + c.y,
                       a.z + b.z + c.z, a.w + b.w + c.w);
}

__global__ __launch_bounds__(NTH) void fused3(
    const float* __restrict__ featp, const int* __restrict__ maskp,
    float4* __restrict__ c2o, float4* __restrict__ c3o)
{
    const int j = blockIdx.x;              // col strip (c3 cols [8j,8j+8))
    const int k = blockIdx.y;              // row chunk (c3 rows [8k,8k+8))
    const int b = blockIdx.z;
    const int P0 = TW3 * j, Q0 = TH3 * k;
    const int F0 = 8 * P0 - 7;             // feat col of u=0,dw=0
    const int S0 = 4 * Q0 - 3;             // first c1 row of sweep

    const int tid = threadIdx.x;
    const int c4 = tid & 3;                // which float4 of 16 channels
    const int u  = tid >> 2;               // col role index
    const bool aAct = tid < NU * 4;        // 140 threads: rs1/c1 role
    const bool vAct = tid < NV * 4;        //  68 threads: rs2/c2 role
    const bool yAct = tid < NY * 4;        //  32 threads: rs3/c3 role

    __shared__ float4 c1m[2][NU][5];       // double-buffered (write pre-bar, read post-bar)
    __shared__ float4 c2mS[NV][5];         // written post-bar(even i), read post-bar(i+1)
    __shared__ unsigned char m1L[2][NU];
    __shared__ unsigned char m2L[NV];

    const float4* feat4 = reinterpret_cast<const float4*>(featp);
    const float4 z4 = make_float4(0.f, 0.f, 0.f, 0.f);

    auto ldMaskRow = [&](int t, int* mm) {
        mm[0] = mm[1] = mm[2] = 0;
        if (aAct && (unsigned)t < (unsigned)Hh) {
            const int base = (b * Hh + t) * Ww;
#pragma unroll
            for (int dw = 0; dw < 3; ++dw) {
                const int fc = F0 + 2 * u + dw;
                if ((unsigned)fc < (unsigned)Ww) mm[dw] = maskp[base + fc];
            }
        }
    };
    auto ldFeatRow = [&](int t, const int* mm, float4* ff) {
        ff[0] = ff[1] = ff[2] = z4;
        if (aAct && (unsigned)t < (unsigned)Hh) {
            const size_t base = (size_t)(b * Hh + t) * Ww;
#pragma unroll
            for (int dw = 0; dw < 3; ++dw) {
                if (mm[dw])   // masked-out pixels are never fetched
                    ff[dw] = feat4[(base + (F0 + 2 * u + dw)) * 4 + c4];
            }
        }
    };

    // ---- prologue: pair 0 resident, pair-1 masks resident, prev-row sum ----
    int   mA[6];        // masks of pair i+1 (entering iter i)
    float4 ffA[6];      // feat of pair i (masked)
    float4 h_prev;      // rowsum of feat row 2s-1
    int   mp_cur;       // m1 occupancy OR for pair i
    {
        int mP[3], m0[6];
        ldMaskRow(2 * S0 - 1, mP);
        ldMaskRow(2 * S0,     m0);
        ldMaskRow(2 * S0 + 1, m0 + 3);
        ldMaskRow(2 * S0 + 2, mA);
        ldMaskRow(2 * S0 + 3, mA + 3);
        float4 fP[3];
        ldFeatRow(2 * S0 - 1, mP, fP);
        ldFeatRow(2 * S0,     m0, ffA);
        ldFeatRow(2 * S0 + 1, m0 + 3, ffA + 3);
        h_prev = add3(fP[0], fP[1], fP[2]);
        mp_cur = m0[1] | m0[2] | m0[4] | m0[5];
    }

    float4 r2h0 = z4, r2h1 = z4;           // rs2 history (s-2, s-1)
    float4 r3h0 = z4, r3h1 = z4;           // rs3 history
    int m2save = 0, m3save = 0;

    for (int i = 0; i < NS; ++i) {
        const int sb = i & 1;
        // A: consume feat pair i -> c1 row s = S0+i (LDS write pre-barrier)
        const float4 hc_e = add3(ffA[0], ffA[1], ffA[2]);
        const float4 hc_o = add3(ffA[3], ffA[4], ffA[5]);
        if (aAct) {
            float4 cv = z4;
            if (mp_cur) cv = add3(h_prev, hc_e, hc_o);
            c1m[sb][u][c4] = cv;
            if (c4 == 0) m1L[sb][u] = (unsigned char)(mp_cur ? 1 : 0);
        }
        const float4 hp_new = hc_o;
        const int mp_new = mA[1] | mA[2] | mA[4] | mA[5];
        // B: prefetch issue — feat pair i+1 (gated by mA), masks pair i+2
        const int t2 = 2 * (S0 + i) + 2;
        if (i + 1 < NS) {
            ldFeatRow(t2,     mA,     ffA);
            ldFeatRow(t2 + 1, mA + 3, ffA + 3);
        }
        if (i + 2 < NS) {
            ldMaskRow(t2 + 2, mA);
            ldMaskRow(t2 + 3, mA + 3);
        }
        BARRIER_LDS();                     // the iteration's single barrier
        // C: r2 phase (post-barrier)
        float4 r2c = z4; int m2p = 0;
        if (vAct) {
            r2c = add3(c1m[sb][2 * u + 0][c4], c1m[sb][2 * u + 1][c4],
                       c1m[sb][2 * u + 2][c4]);
            m2p = m1L[sb][2 * u + 1] | m1L[sb][2 * u + 2];
        }
        if ((i & 1) == 0) {
            // c2 row r = 2*Q0 - 2 + i/2 completes; c2mS consumed at i+1
            if (vAct) {
                const int m2 = m2save | m2p;
                float4 c2v = z4;
                if (m2) c2v = add3(r2h0, r2h1, r2c);
                if (i >= 4 && u >= 1) {    // owned rows r>=2Q0, owned cols
                    const int r = 2 * Q0 - 2 + (i >> 1);
                    c2o[((size_t)((b * 256 + r) * 256 + (2 * P0 - 1 + u))) * 4 + c4] = c2v;
                }
                c2mS[u][c4] = c2v;
                if (c4 == 0) m2L[u] = (unsigned char)(m2 ? 1 : 0);
            }
        } else {
            m2save = m2p;
            // D: r3 phase — reads c2 row written post-barrier at i-1
            float4 r3c = z4; int m3p = 0;
            if (yAct) {
                r3c = add3(c2mS[2 * u + 0][c4], c2mS[2 * u + 1][c4],
                           c2mS[2 * u + 2][c4]);
                m3p = m2L[2 * u + 1] | m2L[2 * u + 2];
            }
            if (((i - 1) & 2) == 0) {      // c2 row even: save
                m3save = m3p;
            } else if (yAct && i >= 7) {   // c2 row odd: c3 row q completes
                const int m3 = m3save | m3p;
                float4 c3v = z4;
                if (m3) c3v = add3(r3h0, r3h1, r3c);
                const int q = Q0 + ((i - 7) >> 2);
                c3o[((size_t)((b * 128 + q) * 128 + (P0 + u))) * 4 + c4] = c3v;
            }
            r3h0 = r3h1; r3h1 = r3c;
        }
        r2h0 = r2h1; r2h1 = r2c;
        h_prev = hp_new; mp_cur = mp_new;
    }
    // epilogue: final r3/c3 (i_eff = NS = 35) reading c2mS written at i = 34
    BARRIER_LDS();
    if (yAct) {
        const float4 r3c = add3(c2mS[2 * u + 0][c4], c2mS[2 * u + 1][c4],
                                c2mS[2 * u + 2][c4]);
        const int m3p = m2L[2 * u + 1] | m2L[2 * u + 2];
        const int m3 = m3save | m3p;
        float4 c3v = z4;
        if (m3) c3v = add3(r3h0, r3h1, r3c);
        const int q = Q0 + ((NS - 7) >> 2);            // Q0 + 7
        c3o[((size_t)((b * 128 + q) * 128 + (P0 + u))) * 4 + c4] = c3v;
    }
}

extern "C" void kernel_launch(void* const* d_in, const int* in_sizes, int n_in,
                              void* d_out, int out_size, void* d_ws, size_t ws_size,
                              hipStream_t stream)
{
    const float* feat = (const float*)d_in[0];
    const int*   mask = (const int*)d_in[1];
    float4* c2 = (float4*)d_out;
    float4* c3 = c2 + (size_t)4 * 256 * 256 * 4;   // 4*256*256*16 floats ahead

    dim3 grid(Ww / (8 * TW3) /*16*/, Hh / (8 * TH3) /*16*/, 4);
    fused3<<<grid, NTH, 0, stream>>>(feat, mask, c2, c3);
}